// Round 1
// baseline (861.425 us; speedup 1.0000x reference)
//
#include <hip/hip_runtime.h>
#include <math.h>

#define N_NODES 100000
#define N_EDGES 1600000
#define DIM     128
#define NCLS    64
#define ALPHA   0.1f

#define SCAN_B  98                 // ceil(100000/1024)
#define NB      391                // ceil(100000/256) dst-buckets of 256 nodes
#define NF      ((size_t)N_NODES * DIM)
#define STRIPES (N_NODES / 16)     // 6250 exact
#define CHUNK   2048               // edges per partition block

typedef __attribute__((ext_vector_type(8))) short  bf16x8;
typedef __attribute__((ext_vector_type(4))) float  f32x4;

// ---- bf16 helpers (storage only; accumulation fp32) ----
__device__ __forceinline__ float bf2f(unsigned short u) {
    return __uint_as_float((unsigned int)u << 16);
}
__device__ __forceinline__ float2 bf2f2(ushort2 u) {
    return make_float2(bf2f(u.x), bf2f(u.y));
}
__device__ __forceinline__ unsigned short f2bf(float x) {
    unsigned int u = __float_as_uint(x);
    u += 0x7FFFu + ((u >> 16) & 1u);          // round-to-nearest-even
    return (unsigned short)(u >> 16);
}
__device__ __forceinline__ ushort2 f2bf2(float2 v) {
    return make_ushort2(f2bf(v.x), f2bf(v.y));
}

// ================= bucketed CSR build =================
// bucket = dst >> 8 (256 nodes/bucket). ebuf entry: x = src | dst_local<<17, y = 0.9*w.

__global__ __launch_bounds__(256) void k_hist(const int* __restrict__ dst,
                                              int* __restrict__ bucket_cnt) {
    __shared__ int hist[NB];
    int t = threadIdx.x;
    for (int b = t; b < NB; b += 256) hist[b] = 0;
    __syncthreads();
    int base = blockIdx.x * CHUNK;
    int end = min(base + CHUNK, N_EDGES);
    for (int i = base + t; i < end; i += 256)
        atomicAdd(&hist[dst[i] >> 8], 1);
    __syncthreads();
    for (int b = t; b < NB; b += 256)
        if (hist[b]) atomicAdd(&bucket_cnt[b], hist[b]);
}

__global__ __launch_bounds__(512) void k_scanb(const int* __restrict__ bucket_cnt,
                                               int* __restrict__ bucket_base,
                                               int* __restrict__ bucket_cursor) {
    __shared__ int s[512];
    int t = threadIdx.x;
    int v = (t < NB) ? bucket_cnt[t] : 0;
    s[t] = v;
    __syncthreads();
    for (int off = 1; off < 512; off <<= 1) {
        int u = (t >= off) ? s[t - off] : 0;
        __syncthreads();
        s[t] += u;
        __syncthreads();
    }
    if (t < NB) {
        int base = s[t] - v;
        bucket_base[t] = base;
        bucket_cursor[t] = base;
    }
    if (t == 0) bucket_base[NB] = N_EDGES;
}

__global__ __launch_bounds__(256) void k_part(const int* __restrict__ src,
                                              const int* __restrict__ dst,
                                              const float* __restrict__ ew,
                                              int* __restrict__ bucket_cursor,
                                              int2* __restrict__ ebuf) {
    __shared__ int lhist[NB], gbase[NB];
    int t = threadIdx.x;
    for (int b = t; b < NB; b += 256) lhist[b] = 0;
    __syncthreads();
    int base = blockIdx.x * CHUNK;
    int end = min(base + CHUNK, N_EDGES);
    for (int i = base + t; i < end; i += 256)
        atomicAdd(&lhist[dst[i] >> 8], 1);
    __syncthreads();
    for (int b = t; b < NB; b += 256) {
        int c = lhist[b];
        gbase[b] = c ? atomicAdd(&bucket_cursor[b], c) : 0;
        lhist[b] = 0;
    }
    __syncthreads();
    for (int i = base + t; i < end; i += 256) {
        int d = dst[i];
        int b = d >> 8;
        int r = atomicAdd(&lhist[b], 1);
        ebuf[gbase[b] + r] = make_int2(src[i] | ((d & 255) << 17),
                                       __float_as_int((1.0f - ALPHA) * ew[i]));
    }
}

// per-bucket degree via LDS counters (no global atomics)
__global__ __launch_bounds__(256) void k_deg(const int2* __restrict__ ebuf,
                                             const int* __restrict__ bucket_base,
                                             int* __restrict__ deg) {
    __shared__ int cnt[256];
    int t = threadIdx.x, b = blockIdx.x;
    cnt[t] = 0;
    __syncthreads();
    int beg = bucket_base[b], end = bucket_base[b + 1];
    for (int i = beg + t; i < end; i += 256)
        atomicAdd(&cnt[ebuf[i].x >> 17], 1);
    __syncthreads();
    int node = b * 256 + t;
    if (node < N_NODES) deg[node] = cnt[t];
}

__global__ __launch_bounds__(1024) void k_scan1(const int* __restrict__ deg,
                                                int* __restrict__ row_ptr,
                                                int* __restrict__ blocksum) {
    __shared__ int s[1024];
    int t = threadIdx.x;
    int i = blockIdx.x * 1024 + t;
    int v = (i < N_NODES) ? deg[i] : 0;
    s[t] = v;
    __syncthreads();
    for (int off = 1; off < 1024; off <<= 1) {
        int u = (t >= off) ? s[t - off] : 0;
        __syncthreads();
        s[t] += u;
        __syncthreads();
    }
    if (i < N_NODES) row_ptr[i] = s[t] - v;
    if (t == 1023) blocksum[blockIdx.x] = s[1023];
}

__global__ __launch_bounds__(128) void k_scan2(int* __restrict__ blocksum) {
    __shared__ int s[128];
    int t = threadIdx.x;
    int v = (t < SCAN_B) ? blocksum[t] : 0;
    s[t] = v;
    __syncthreads();
    for (int off = 1; off < 128; off <<= 1) {
        int u = (t >= off) ? s[t - off] : 0;
        __syncthreads();
        s[t] += u;
        __syncthreads();
    }
    if (t < SCAN_B) blocksum[t] = s[t] - v;
}

__global__ __launch_bounds__(1024) void k_scan3(int* __restrict__ row_ptr,
                                                const int* __restrict__ blocksum) {
    int t = threadIdx.x;
    int i = blockIdx.x * 1024 + t;
    if (i < N_NODES) row_ptr[i] += blocksum[blockIdx.x];
    if (i == 0) row_ptr[N_NODES] = N_EDGES;
}

// per-bucket counting-sort scatter; LDS cursors, colw writes confined to ~32KB
__global__ __launch_bounds__(256) void k_scatter2(const int2* __restrict__ ebuf,
                                                  const int* __restrict__ bucket_base,
                                                  const int* __restrict__ row_ptr,
                                                  int2* __restrict__ colw) {
    __shared__ int lcur[256];
    int t = threadIdx.x, b = blockIdx.x;
    int node = b * 256 + t;
    lcur[t] = (node < N_NODES) ? row_ptr[node] : 0;
    __syncthreads();
    int beg = bucket_base[b], end = bucket_base[b + 1];
    for (int i = beg + t; i < end; i += 256) {
        int2 e = ebuf[i];
        int pos = atomicAdd(&lcur[e.x >> 17], 1);
        colw[pos] = make_int2(e.x & 0x1FFFF, e.y);
    }
}

// ===== weight pack: fp32 -> bf16 B-fragment order =====
// frag idx = ((nt*4 + ch)*64 + lane)*8 + j ;
// value = W[ch*32 + (lane>>4)*8 + j][nt*16 + (lane&15)]
// layers at wp[l*16384] (l=0..3), w_out at wp[65536] (nt 0..3), w_in at wp[73728].
__global__ void k_prepw(const float* __restrict__ gcnw, const float* __restrict__ wout,
                        const float* __restrict__ win, unsigned short* __restrict__ wp) {
    int tid = blockIdx.x * 256 + threadIdx.x;
    if (tid < 65536) {
        int l = tid >> 14;
        int r = tid & 16383;
        int j = r & 7, lane = (r >> 3) & 63, ch = (r >> 9) & 3, nt = r >> 11;
        int n = nt * 16 + (lane & 15);
        int k = ch * 32 + (lane >> 4) * 8 + j;
        wp[tid] = f2bf(gcnw[l * 16384 + k * 128 + n]);
    } else if (tid < 73728) {
        int r = tid - 65536;
        int j = r & 7, lane = (r >> 3) & 63, ch = (r >> 9) & 3, nt = r >> 11; // nt 0..3
        int n = nt * 16 + (lane & 15);
        int k = ch * 32 + (lane >> 4) * 8 + j;
        wp[tid] = f2bf(wout[k * 64 + n]);
    } else if (tid < 90112) {
        int r = tid - 73728;
        int j = r & 7, lane = (r >> 3) & 63, ch = (r >> 9) & 3, nt = r >> 11; // nt 0..7
        int n = nt * 16 + (lane & 15);
        int k = ch * 32 + (lane >> 4) * 8 + j;
        wp[tid] = f2bf(win[k * 128 + n]);
    }
}

// ===== MFMA input GEMM: h0 = relu(x @ W_in + b)  (x fp32 -> bf16 in-reg) =====
__global__ __launch_bounds__(256) void k_in_mfma(
    const float* __restrict__ x, const unsigned short* __restrict__ wp,
    const float* __restrict__ b_in, unsigned short* __restrict__ h0) {
    int wave = threadIdx.x >> 6, lane = threadIdx.x & 63;
    int stripe = blockIdx.x * 4 + wave;
    if (stripe >= STRIPES) return;
    int r0 = stripe * 16;
    int m = lane & 15, q = lane >> 4;

    f32x4 acc[8];
    #pragma unroll
    for (int nt = 0; nt < 8; nt++) acc[nt] = (f32x4){0.f, 0.f, 0.f, 0.f};

    const float* xr = x + (size_t)(r0 + m) * DIM + q * 8;
    #pragma unroll
    for (int ch = 0; ch < 4; ch++) {
        float4 a0 = *(const float4*)(xr + ch * 32);
        float4 a1 = *(const float4*)(xr + ch * 32 + 4);
        bf16x8 a;
        a[0] = (short)f2bf(a0.x); a[1] = (short)f2bf(a0.y);
        a[2] = (short)f2bf(a0.z); a[3] = (short)f2bf(a0.w);
        a[4] = (short)f2bf(a1.x); a[5] = (short)f2bf(a1.y);
        a[6] = (short)f2bf(a1.z); a[7] = (short)f2bf(a1.w);
        #pragma unroll
        for (int nt = 0; nt < 8; nt++) {
            bf16x8 b = *(const bf16x8*)(wp + (((nt * 4 + ch) * 64 + lane) << 3));
            acc[nt] = __builtin_amdgcn_mfma_f32_16x16x32_bf16(a, b, acc[nt], 0, 0, 0);
        }
    }

    #pragma unroll
    for (int nt = 0; nt < 8; nt++) {
        int col = nt * 16 + m;
        float bias = b_in[col];
        #pragma unroll
        for (int r = 0; r < 4; r++) {
            int row = r0 + q * 4 + r;
            h0[(size_t)row * DIM + col] = f2bf(fmaxf(acc[nt][r] + bias, 0.f));
        }
    }
}

// ===== FUSED layer: SpMM(16 nodes)->LDS(bf16, XOR-swizzled), then
//       h = relu(theta*(sup@W) + (1-theta)*sup + hprev). One stripe per wave.
// LDS linear model per wave: sup16[row][128] ushort. 16B slots swizzled:
//   slot' = slot ^ (row & 7). Write = ushort2/lane (2-way banks, free);
//   A-read = bf16x8 (structural-minimum 8/bank); epilogue = scalar u16.
__global__ __launch_bounds__(256, 4) void k_layer_fused(
    const int* __restrict__ row_ptr, const int2* __restrict__ colw,
    const unsigned short* __restrict__ hprev, const unsigned short* __restrict__ h0,
    const unsigned short* __restrict__ wp, unsigned short* __restrict__ hout,
    float theta) {
    __shared__ unsigned short sup[4][16 * 128];   // 4 waves x 4KB
    int wave = threadIdx.x >> 6, lane = threadIdx.x & 63;
    int stripe = blockIdx.x * 4 + wave;
    unsigned short* ws = sup[wave];
    int m = lane & 15, q = lane >> 4;
    float omt = 1.f - theta;

    // ---- phase 1: SpMM 16 nodes into wave-private swizzled LDS ----
    if (stripe < STRIPES) {
        int r0 = stripe * 16;
        for (int i = 0; i < 16; i++) {
            int node = r0 + i;
            int beg = row_ptr[node], end = row_ptr[node + 1];
            float2 z = bf2f2(((const ushort2*)(h0 + (size_t)node * DIM))[lane]);
            float2 acc = make_float2(ALPHA * z.x, ALPHA * z.y);
            int e = beg;
            for (; e + 3 < end; e += 4) {
                int2 c0 = colw[e];
                int2 c1 = colw[e + 1];
                int2 c2 = colw[e + 2];
                int2 c3 = colw[e + 3];
                float2 v0 = bf2f2(((const ushort2*)(hprev + (size_t)c0.x * DIM))[lane]);
                float2 v1 = bf2f2(((const ushort2*)(hprev + (size_t)c1.x * DIM))[lane]);
                float2 v2 = bf2f2(((const ushort2*)(hprev + (size_t)c2.x * DIM))[lane]);
                float2 v3 = bf2f2(((const ushort2*)(hprev + (size_t)c3.x * DIM))[lane]);
                float w0 = __int_as_float(c0.y), w1 = __int_as_float(c1.y);
                float w2 = __int_as_float(c2.y), w3 = __int_as_float(c3.y);
                acc.x += w0 * v0.x + w1 * v1.x + w2 * v2.x + w3 * v3.x;
                acc.y += w0 * v0.y + w1 * v1.y + w2 * v2.y + w3 * v3.y;
            }
            for (; e < end; e++) {
                int2 c0 = colw[e];
                float2 v0 = bf2f2(((const ushort2*)(hprev + (size_t)c0.x * DIM))[lane]);
                float w0 = __int_as_float(c0.y);
                acc.x += w0 * v0.x;
                acc.y += w0 * v0.y;
            }
            // linear ushort idx = i*128 + lane*2 ; 16B-slot = lane>>2, swizzle ^= (i&7)
            int sl = (lane >> 2) ^ (i & 7);
            ((ushort2*)ws)[i * 64 + sl * 4 + (lane & 3)] = f2bf2(acc);
        }
    }
    __syncthreads();   // uniform: all 256 threads reach this

    // ---- phase 2: MFMA from LDS + epilogue ----
    if (stripe < STRIPES) {
        int r0 = stripe * 16;
        f32x4 acc[8];
        #pragma unroll
        for (int nt = 0; nt < 8; nt++) acc[nt] = (f32x4){0.f, 0.f, 0.f, 0.f};

        #pragma unroll
        for (int ch = 0; ch < 4; ch++) {
            // A row m, dims q*8+ch*32 : slot = q+4ch, swizzle ^= (m&7)
            int sl = (q + 4 * ch) ^ (m & 7);
            bf16x8 a = *(const bf16x8*)(ws + m * 128 + sl * 8);
            #pragma unroll
            for (int nt = 0; nt < 8; nt++) {
                bf16x8 b = *(const bf16x8*)(wp + (((nt * 4 + ch) * 64 + lane) << 3));
                acc[nt] = __builtin_amdgcn_mfma_f32_16x16x32_bf16(a, b, acc[nt], 0, 0, 0);
            }
        }

        #pragma unroll
        for (int nt = 0; nt < 8; nt++) {
            int col = nt * 16 + m;
            #pragma unroll
            for (int r = 0; r < 4; r++) {
                int rl = q * 4 + r;
                int row = r0 + rl;
                int sl = (col >> 3) ^ (rl & 7);
                float supv = bf2f(ws[rl * 128 + sl * 8 + (col & 7)]);
                float hp = bf2f(hprev[(size_t)row * DIM + col]);
                float o = theta * acc[nt][r] + omt * supv + hp;
                hout[(size_t)row * DIM + col] = f2bf(fmaxf(o, 0.f));
            }
        }
    }
}

// ===== MFMA output GEMM + log_softmax =====
__global__ __launch_bounds__(256) void k_out_mfma(
    const unsigned short* __restrict__ h, const unsigned short* __restrict__ wp,
    const float* __restrict__ bo, float* __restrict__ out) {
    int wave = threadIdx.x >> 6, lane = threadIdx.x & 63;
    int stripe = blockIdx.x * 4 + wave;
    if (stripe >= STRIPES) return;
    int r0 = stripe * 16;
    int m = lane & 15, q = lane >> 4;

    f32x4 acc[4];
    #pragma unroll
    for (int nt = 0; nt < 4; nt++) acc[nt] = (f32x4){0.f, 0.f, 0.f, 0.f};

    const unsigned short* arow = h + (size_t)(r0 + m) * DIM + q * 8;
    #pragma unroll
    for (int ch = 0; ch < 4; ch++) {
        bf16x8 a = *(const bf16x8*)(arow + ch * 32);
        #pragma unroll
        for (int nt = 0; nt < 4; nt++) {
            bf16x8 b = *(const bf16x8*)(wp + (((nt * 4 + ch) * 64 + lane) << 3));
            acc[nt] = __builtin_amdgcn_mfma_f32_16x16x32_bf16(a, b, acc[nt], 0, 0, 0);
        }
    }

    float v[4][4];
    #pragma unroll
    for (int nt = 0; nt < 4; nt++) {
        float bias = bo[nt * 16 + m];
        #pragma unroll
        for (int r = 0; r < 4; r++) v[nt][r] = acc[nt][r] + bias;
    }
    #pragma unroll
    for (int r = 0; r < 4; r++) {
        float mx = fmaxf(fmaxf(v[0][r], v[1][r]), fmaxf(v[2][r], v[3][r]));
        #pragma unroll
        for (int off = 1; off < 16; off <<= 1) mx = fmaxf(mx, __shfl_xor(mx, off));
        float s = 0.f;
        #pragma unroll
        for (int nt = 0; nt < 4; nt++) s += __expf(v[nt][r] - mx);
        #pragma unroll
        for (int off = 1; off < 16; off <<= 1) s += __shfl_xor(s, off);
        float lse = mx + logf(s);
        int row = r0 + q * 4 + r;
        #pragma unroll
        for (int nt = 0; nt < 4; nt++)
            out[(size_t)row * NCLS + nt * 16 + m] = v[nt][r] - lse;
    }
}

extern "C" void kernel_launch(void* const* d_in, const int* in_sizes, int n_in,
                              void* d_out, int out_size, void* d_ws, size_t ws_size,
                              hipStream_t stream) {
    const float* x    = (const float*)d_in[0];
    const int*   esrc = (const int*)d_in[1];
    const int*   edst = (const int*)d_in[2];
    const float* ew   = (const float*)d_in[3];
    const float* w_in = (const float*)d_in[4];
    const float* b_in = (const float*)d_in[5];
    const float* gcnw = (const float*)d_in[6];   // [4,128,128]
    const float* wout = (const float*)d_in[7];
    const float* bout = (const float*)d_in[8];
    float* out = (float*)d_out;

    // workspace layout (hi slot retained but unused by the fused path)
    unsigned short* h0 = (unsigned short*)d_ws;        // NF ushorts each
    unsigned short* hA = h0 + NF;
    unsigned short* hB = hA + NF;
    unsigned short* hi = hB + NF;
    unsigned short* wp = hi + NF;                      // 90112 ushorts packed W
    int2* colw = (int2*)(wp + 90112);                  // E int2
    int2* ebuf = colw + N_EDGES;                       // E int2 (bucket-grouped)
    int*  row_ptr       = (int*)(ebuf + N_EDGES);      // N+1
    int*  deg           = row_ptr + (N_NODES + 1);     // N
    int*  blocksum      = deg + N_NODES;               // SCAN_B
    int*  bucket_cnt    = blocksum + SCAN_B;           // NB
    int*  bucket_base   = bucket_cnt + NB;             // NB+1
    int*  bucket_cursor = bucket_base + (NB + 1);      // NB

    const int PART_B = (N_EDGES + CHUNK - 1) / CHUNK;  // 782
    const int MFMA_BLOCKS = (STRIPES + 3) / 4;         // 1563

    // ---- weight pack ----
    k_prepw<<<(90112 + 255) / 256, 256, 0, stream>>>(gcnw, wout, w_in, wp);

    // ---- bucketed CSR build ----
    hipMemsetAsync(bucket_cnt, 0, NB * sizeof(int), stream);
    k_hist<<<PART_B, 256, 0, stream>>>(edst, bucket_cnt);
    k_scanb<<<1, 512, 0, stream>>>(bucket_cnt, bucket_base, bucket_cursor);
    k_part<<<PART_B, 256, 0, stream>>>(esrc, edst, ew, bucket_cursor, ebuf);
    k_deg<<<NB, 256, 0, stream>>>(ebuf, bucket_base, deg);
    k_scan1<<<SCAN_B, 1024, 0, stream>>>(deg, row_ptr, blocksum);
    k_scan2<<<1, 128, 0, stream>>>(blocksum);
    k_scan3<<<SCAN_B, 1024, 0, stream>>>(row_ptr, blocksum);
    k_scatter2<<<NB, 256, 0, stream>>>(ebuf, bucket_base, row_ptr, colw);

    // h0 = relu(x @ w_in + b_in)
    k_in_mfma<<<MFMA_BLOCKS, 256, 0, stream>>>(x, wp + 73728, b_in, h0);

    const unsigned short* hprev = h0;
    unsigned short* bufs[2] = {hA, hB};
    for (int l = 0; l < 4; l++) {
        float theta = logf(0.5f / (float)(l + 2) + 1.0f);
        unsigned short* hnew = bufs[l & 1];
        k_layer_fused<<<MFMA_BLOCKS, 256, 0, stream>>>(row_ptr, colw, hprev, h0,
                                                       wp + (size_t)l * 16384,
                                                       hnew, theta);
        hprev = hnew;
    }

    // out = log_softmax(h @ w_out + b_out)
    k_out_mfma<<<MFMA_BLOCKS, 256, 0, stream>>>(hprev, wp + 65536, bout, out);
}

// Round 4
// 601.575 us; speedup vs baseline: 1.4319x; 1.4319x over previous
//
#include <hip/hip_runtime.h>
#include <math.h>

#define N_NODES 100000
#define N_EDGES 1600000
#define DIM     128
#define NCLS    64
#define ALPHA   0.1f

#define SCAN_B  98                 // ceil(100000/1024)
#define NB      391                // ceil(100000/256) dst-buckets of 256 nodes
#define NF      ((size_t)N_NODES * DIM)
#define STRIPES (N_NODES / 16)     // 6250 exact
#define CHUNK   2048               // edges per partition block

typedef __attribute__((ext_vector_type(8))) short  bf16x8;
typedef __attribute__((ext_vector_type(4))) float  f32x4;

// ---- bf16 helpers (storage only; accumulation fp32) ----
__device__ __forceinline__ float bf2f(unsigned short u) {
    return __uint_as_float((unsigned int)u << 16);
}
__device__ __forceinline__ float2 bf2f2(ushort2 u) {
    return make_float2(bf2f(u.x), bf2f(u.y));
}
__device__ __forceinline__ unsigned short f2bf(float x) {
    unsigned int u = __float_as_uint(x);
    u += 0x7FFFu + ((u >> 16) & 1u);          // round-to-nearest-even
    return (unsigned short)(u >> 16);
}
__device__ __forceinline__ ushort2 f2bf2(float2 v) {
    return make_ushort2(f2bf(v.x), f2bf(v.y));
}

// ================= bucketed CSR build =================
// bucket = dst >> 8 (256 nodes/bucket). ebuf entry: x = src | dst_local<<17, y = 0.9*w.

__global__ __launch_bounds__(256) void k_hist(const int* __restrict__ dst,
                                              int* __restrict__ bucket_cnt) {
    __shared__ int hist[NB];
    int t = threadIdx.x;
    for (int b = t; b < NB; b += 256) hist[b] = 0;
    __syncthreads();
    int base = blockIdx.x * CHUNK;
    int end = min(base + CHUNK, N_EDGES);
    for (int i = base + t; i < end; i += 256)
        atomicAdd(&hist[dst[i] >> 8], 1);
    __syncthreads();
    for (int b = t; b < NB; b += 256)
        if (hist[b]) atomicAdd(&bucket_cnt[b], hist[b]);
}

__global__ __launch_bounds__(512) void k_scanb(const int* __restrict__ bucket_cnt,
                                               int* __restrict__ bucket_base,
                                               int* __restrict__ bucket_cursor) {
    __shared__ int s[512];
    int t = threadIdx.x;
    int v = (t < NB) ? bucket_cnt[t] : 0;
    s[t] = v;
    __syncthreads();
    for (int off = 1; off < 512; off <<= 1) {
        int u = (t >= off) ? s[t - off] : 0;
        __syncthreads();
        s[t] += u;
        __syncthreads();
    }
    if (t < NB) {
        int base = s[t] - v;
        bucket_base[t] = base;
        bucket_cursor[t] = base;
    }
    if (t == 0) bucket_base[NB] = N_EDGES;
}

__global__ __launch_bounds__(256) void k_part(const int* __restrict__ src,
                                              const int* __restrict__ dst,
                                              const float* __restrict__ ew,
                                              int* __restrict__ bucket_cursor,
                                              int2* __restrict__ ebuf) {
    __shared__ int lhist[NB], gbase[NB];
    int t = threadIdx.x;
    for (int b = t; b < NB; b += 256) lhist[b] = 0;
    __syncthreads();
    int base = blockIdx.x * CHUNK;
    int end = min(base + CHUNK, N_EDGES);
    for (int i = base + t; i < end; i += 256)
        atomicAdd(&lhist[dst[i] >> 8], 1);
    __syncthreads();
    for (int b = t; b < NB; b += 256) {
        int c = lhist[b];
        gbase[b] = c ? atomicAdd(&bucket_cursor[b], c) : 0;
        lhist[b] = 0;
    }
    __syncthreads();
    for (int i = base + t; i < end; i += 256) {
        int d = dst[i];
        int b = d >> 8;
        int r = atomicAdd(&lhist[b], 1);
        ebuf[gbase[b] + r] = make_int2(src[i] | ((d & 255) << 17),
                                       __float_as_int((1.0f - ALPHA) * ew[i]));
    }
}

// per-bucket degree via LDS counters (no global atomics)
__global__ __launch_bounds__(256) void k_deg(const int2* __restrict__ ebuf,
                                             const int* __restrict__ bucket_base,
                                             int* __restrict__ deg) {
    __shared__ int cnt[256];
    int t = threadIdx.x, b = blockIdx.x;
    cnt[t] = 0;
    __syncthreads();
    int beg = bucket_base[b], end = bucket_base[b + 1];
    for (int i = beg + t; i < end; i += 256)
        atomicAdd(&cnt[ebuf[i].x >> 17], 1);
    __syncthreads();
    int node = b * 256 + t;
    if (node < N_NODES) deg[node] = cnt[t];
}

__global__ __launch_bounds__(1024) void k_scan1(const int* __restrict__ deg,
                                                int* __restrict__ row_ptr,
                                                int* __restrict__ blocksum) {
    __shared__ int s[1024];
    int t = threadIdx.x;
    int i = blockIdx.x * 1024 + t;
    int v = (i < N_NODES) ? deg[i] : 0;
    s[t] = v;
    __syncthreads();
    for (int off = 1; off < 1024; off <<= 1) {
        int u = (t >= off) ? s[t - off] : 0;
        __syncthreads();
        s[t] += u;
        __syncthreads();
    }
    if (i < N_NODES) row_ptr[i] = s[t] - v;
    if (t == 1023) blocksum[blockIdx.x] = s[1023];
}

__global__ __launch_bounds__(128) void k_scan2(int* __restrict__ blocksum) {
    __shared__ int s[128];
    int t = threadIdx.x;
    int v = (t < SCAN_B) ? blocksum[t] : 0;
    s[t] = v;
    __syncthreads();
    for (int off = 1; off < 128; off <<= 1) {
        int u = (t >= off) ? s[t - off] : 0;
        __syncthreads();
        s[t] += u;
        __syncthreads();
    }
    if (t < SCAN_B) blocksum[t] = s[t] - v;
}

__global__ __launch_bounds__(1024) void k_scan3(int* __restrict__ row_ptr,
                                                const int* __restrict__ blocksum) {
    int t = threadIdx.x;
    int i = blockIdx.x * 1024 + t;
    if (i < N_NODES) row_ptr[i] += blocksum[blockIdx.x];
    if (i == 0) row_ptr[N_NODES] = N_EDGES;
}

// per-bucket counting-sort scatter; LDS cursors, colw writes confined to ~32KB
__global__ __launch_bounds__(256) void k_scatter2(const int2* __restrict__ ebuf,
                                                  const int* __restrict__ bucket_base,
                                                  const int* __restrict__ row_ptr,
                                                  int2* __restrict__ colw) {
    __shared__ int lcur[256];
    int t = threadIdx.x, b = blockIdx.x;
    int node = b * 256 + t;
    lcur[t] = (node < N_NODES) ? row_ptr[node] : 0;
    __syncthreads();
    int beg = bucket_base[b], end = bucket_base[b + 1];
    for (int i = beg + t; i < end; i += 256) {
        int2 e = ebuf[i];
        int pos = atomicAdd(&lcur[e.x >> 17], 1);
        colw[pos] = make_int2(e.x & 0x1FFFF, e.y);
    }
}

// ===== weight pack: fp32 -> bf16 B-fragment order =====
// frag idx = ((nt*4 + ch)*64 + lane)*8 + j ;
// value = W[ch*32 + (lane>>4)*8 + j][nt*16 + (lane&15)]
// layers at wp[l*16384] (l=0..3), w_out at wp[65536] (nt 0..3), w_in at wp[73728].
__global__ void k_prepw(const float* __restrict__ gcnw, const float* __restrict__ wout,
                        const float* __restrict__ win, unsigned short* __restrict__ wp) {
    int tid = blockIdx.x * 256 + threadIdx.x;
    if (tid < 65536) {
        int l = tid >> 14;
        int r = tid & 16383;
        int j = r & 7, lane = (r >> 3) & 63, ch = (r >> 9) & 3, nt = r >> 11;
        int n = nt * 16 + (lane & 15);
        int k = ch * 32 + (lane >> 4) * 8 + j;
        wp[tid] = f2bf(gcnw[l * 16384 + k * 128 + n]);
    } else if (tid < 73728) {
        int r = tid - 65536;
        int j = r & 7, lane = (r >> 3) & 63, ch = (r >> 9) & 3, nt = r >> 11; // nt 0..3
        int n = nt * 16 + (lane & 15);
        int k = ch * 32 + (lane >> 4) * 8 + j;
        wp[tid] = f2bf(wout[k * 64 + n]);
    } else if (tid < 90112) {
        int r = tid - 73728;
        int j = r & 7, lane = (r >> 3) & 63, ch = (r >> 9) & 3, nt = r >> 11; // nt 0..7
        int n = nt * 16 + (lane & 15);
        int k = ch * 32 + (lane >> 4) * 8 + j;
        wp[tid] = f2bf(win[k * 128 + n]);
    }
}

// ===== SpMM gather (bf16 rows): hi[i] = ALPHA*h0[i] + sum_e w*h[src] =====
// R1 change: 8 row-gathers in flight per wave (was 4) to attack gather latency.
__global__ __launch_bounds__(256, 8) void k_spmm_csr(
    const int* __restrict__ row_ptr, const int2* __restrict__ colw,
    const unsigned short* __restrict__ h, const unsigned short* __restrict__ h0,
    unsigned short* __restrict__ out) {
    int node = blockIdx.x * 4 + (threadIdx.x >> 6);
    if (node >= N_NODES) return;
    int lane = threadIdx.x & 63;
    int beg = row_ptr[node], end = row_ptr[node + 1];

    float2 z = bf2f2(((const ushort2*)(h0 + (size_t)node * DIM))[lane]);
    float2 acc = make_float2(ALPHA * z.x, ALPHA * z.y);

    int e = beg;
    for (; e + 7 < end; e += 8) {
        int2 c0 = colw[e];
        int2 c1 = colw[e + 1];
        int2 c2 = colw[e + 2];
        int2 c3 = colw[e + 3];
        int2 c4 = colw[e + 4];
        int2 c5 = colw[e + 5];
        int2 c6 = colw[e + 6];
        int2 c7 = colw[e + 7];
        float2 v0 = bf2f2(((const ushort2*)(h + (size_t)c0.x * DIM))[lane]);
        float2 v1 = bf2f2(((const ushort2*)(h + (size_t)c1.x * DIM))[lane]);
        float2 v2 = bf2f2(((const ushort2*)(h + (size_t)c2.x * DIM))[lane]);
        float2 v3 = bf2f2(((const ushort2*)(h + (size_t)c3.x * DIM))[lane]);
        float2 v4 = bf2f2(((const ushort2*)(h + (size_t)c4.x * DIM))[lane]);
        float2 v5 = bf2f2(((const ushort2*)(h + (size_t)c5.x * DIM))[lane]);
        float2 v6 = bf2f2(((const ushort2*)(h + (size_t)c6.x * DIM))[lane]);
        float2 v7 = bf2f2(((const ushort2*)(h + (size_t)c7.x * DIM))[lane]);
        float w0 = __int_as_float(c0.y), w1 = __int_as_float(c1.y);
        float w2 = __int_as_float(c2.y), w3 = __int_as_float(c3.y);
        float w4 = __int_as_float(c4.y), w5 = __int_as_float(c5.y);
        float w6 = __int_as_float(c6.y), w7 = __int_as_float(c7.y);
        acc.x += w0 * v0.x + w1 * v1.x + w2 * v2.x + w3 * v3.x;
        acc.y += w0 * v0.y + w1 * v1.y + w2 * v2.y + w3 * v3.y;
        acc.x += w4 * v4.x + w5 * v5.x + w6 * v6.x + w7 * v7.x;
        acc.y += w4 * v4.y + w5 * v5.y + w6 * v6.y + w7 * v7.y;
    }
    for (; e + 3 < end; e += 4) {
        int2 c0 = colw[e];
        int2 c1 = colw[e + 1];
        int2 c2 = colw[e + 2];
        int2 c3 = colw[e + 3];
        float2 v0 = bf2f2(((const ushort2*)(h + (size_t)c0.x * DIM))[lane]);
        float2 v1 = bf2f2(((const ushort2*)(h + (size_t)c1.x * DIM))[lane]);
        float2 v2 = bf2f2(((const ushort2*)(h + (size_t)c2.x * DIM))[lane]);
        float2 v3 = bf2f2(((const ushort2*)(h + (size_t)c3.x * DIM))[lane]);
        float w0 = __int_as_float(c0.y), w1 = __int_as_float(c1.y);
        float w2 = __int_as_float(c2.y), w3 = __int_as_float(c3.y);
        acc.x += w0 * v0.x + w1 * v1.x + w2 * v2.x + w3 * v3.x;
        acc.y += w0 * v0.y + w1 * v1.y + w2 * v2.y + w3 * v3.y;
    }
    for (; e < end; e++) {
        int2 c0 = colw[e];
        float2 v0 = bf2f2(((const ushort2*)(h + (size_t)c0.x * DIM))[lane]);
        float w0 = __int_as_float(c0.y);
        acc.x += w0 * v0.x;
        acc.y += w0 * v0.y;
    }
    ((ushort2*)(out + (size_t)node * DIM))[lane] = f2bf2(acc);
}

// ===== MFMA input GEMM: h0 = relu(x @ W_in + b)  (x fp32 -> bf16 in-reg) =====
__global__ __launch_bounds__(256) void k_in_mfma(
    const float* __restrict__ x, const unsigned short* __restrict__ wp,
    const float* __restrict__ b_in, unsigned short* __restrict__ h0) {
    int wave = threadIdx.x >> 6, lane = threadIdx.x & 63;
    int stripe = blockIdx.x * 4 + wave;
    if (stripe >= STRIPES) return;
    int r0 = stripe * 16;
    int m = lane & 15, q = lane >> 4;

    f32x4 acc[8];
    #pragma unroll
    for (int nt = 0; nt < 8; nt++) acc[nt] = (f32x4){0.f, 0.f, 0.f, 0.f};

    const float* xr = x + (size_t)(r0 + m) * DIM + q * 8;
    #pragma unroll
    for (int ch = 0; ch < 4; ch++) {
        float4 a0 = *(const float4*)(xr + ch * 32);
        float4 a1 = *(const float4*)(xr + ch * 32 + 4);
        bf16x8 a;
        a[0] = (short)f2bf(a0.x); a[1] = (short)f2bf(a0.y);
        a[2] = (short)f2bf(a0.z); a[3] = (short)f2bf(a0.w);
        a[4] = (short)f2bf(a1.x); a[5] = (short)f2bf(a1.y);
        a[6] = (short)f2bf(a1.z); a[7] = (short)f2bf(a1.w);
        #pragma unroll
        for (int nt = 0; nt < 8; nt++) {
            bf16x8 b = *(const bf16x8*)(wp + (((nt * 4 + ch) * 64 + lane) << 3));
            acc[nt] = __builtin_amdgcn_mfma_f32_16x16x32_bf16(a, b, acc[nt], 0, 0, 0);
        }
    }

    #pragma unroll
    for (int nt = 0; nt < 8; nt++) {
        int col = nt * 16 + m;
        float bias = b_in[col];
        #pragma unroll
        for (int r = 0; r < 4; r++) {
            int row = r0 + q * 4 + r;
            h0[(size_t)row * DIM + col] = f2bf(fmaxf(acc[nt][r] + bias, 0.f));
        }
    }
}

// ===== MFMA layer GEMM: h = relu(theta*(s@W) + (1-theta)*s + hprev) =====
__global__ __launch_bounds__(256) void k_layer_mfma(
    const unsigned short* __restrict__ s_in, const unsigned short* __restrict__ hprev,
    const unsigned short* __restrict__ wp, unsigned short* __restrict__ hout,
    float theta) {
    int wave = threadIdx.x >> 6, lane = threadIdx.x & 63;
    int stripe = blockIdx.x * 4 + wave;
    if (stripe >= STRIPES) return;
    int r0 = stripe * 16;
    int m = lane & 15, q = lane >> 4;
    float omt = 1.f - theta;

    f32x4 acc[8];
    #pragma unroll
    for (int nt = 0; nt < 8; nt++) acc[nt] = (f32x4){0.f, 0.f, 0.f, 0.f};

    const unsigned short* arow = s_in + (size_t)(r0 + m) * DIM + q * 8;
    #pragma unroll
    for (int ch = 0; ch < 4; ch++) {
        bf16x8 a = *(const bf16x8*)(arow + ch * 32);
        #pragma unroll
        for (int nt = 0; nt < 8; nt++) {
            bf16x8 b = *(const bf16x8*)(wp + (((nt * 4 + ch) * 64 + lane) << 3));
            acc[nt] = __builtin_amdgcn_mfma_f32_16x16x32_bf16(a, b, acc[nt], 0, 0, 0);
        }
    }

    #pragma unroll
    for (int nt = 0; nt < 8; nt++) {
        int col = nt * 16 + m;
        #pragma unroll
        for (int r = 0; r < 4; r++) {
            int row = r0 + q * 4 + r;
            size_t idx = (size_t)row * DIM + col;
            float sup = bf2f(s_in[idx]);
            float hp  = bf2f(hprev[idx]);
            float o = theta * acc[nt][r] + omt * sup + hp;
            hout[idx] = f2bf(fmaxf(o, 0.f));
        }
    }
}

// ===== MFMA output GEMM + log_softmax =====
__global__ __launch_bounds__(256) void k_out_mfma(
    const unsigned short* __restrict__ h, const unsigned short* __restrict__ wp,
    const float* __restrict__ bo, float* __restrict__ out) {
    int wave = threadIdx.x >> 6, lane = threadIdx.x & 63;
    int stripe = blockIdx.x * 4 + wave;
    if (stripe >= STRIPES) return;
    int r0 = stripe * 16;
    int m = lane & 15, q = lane >> 4;

    f32x4 acc[4];
    #pragma unroll
    for (int nt = 0; nt < 4; nt++) acc[nt] = (f32x4){0.f, 0.f, 0.f, 0.f};

    const unsigned short* arow = h + (size_t)(r0 + m) * DIM + q * 8;
    #pragma unroll
    for (int ch = 0; ch < 4; ch++) {
        bf16x8 a = *(const bf16x8*)(arow + ch * 32);
        #pragma unroll
        for (int nt = 0; nt < 4; nt++) {
            bf16x8 b = *(const bf16x8*)(wp + (((nt * 4 + ch) * 64 + lane) << 3));
            acc[nt] = __builtin_amdgcn_mfma_f32_16x16x32_bf16(a, b, acc[nt], 0, 0, 0);
        }
    }

    float v[4][4];
    #pragma unroll
    for (int nt = 0; nt < 4; nt++) {
        float bias = bo[nt * 16 + m];
        #pragma unroll
        for (int r = 0; r < 4; r++) v[nt][r] = acc[nt][r] + bias;
    }
    #pragma unroll
    for (int r = 0; r < 4; r++) {
        float mx = fmaxf(fmaxf(v[0][r], v[1][r]), fmaxf(v[2][r], v[3][r]));
        #pragma unroll
        for (int off = 1; off < 16; off <<= 1) mx = fmaxf(mx, __shfl_xor(mx, off));
        float s = 0.f;
        #pragma unroll
        for (int nt = 0; nt < 4; nt++) s += __expf(v[nt][r] - mx);
        #pragma unroll
        for (int off = 1; off < 16; off <<= 1) s += __shfl_xor(s, off);
        float lse = mx + logf(s);
        int row = r0 + q * 4 + r;
        #pragma unroll
        for (int nt = 0; nt < 4; nt++)
            out[(size_t)row * NCLS + nt * 16 + m] = v[nt][r] - lse;
    }
}

extern "C" void kernel_launch(void* const* d_in, const int* in_sizes, int n_in,
                              void* d_out, int out_size, void* d_ws, size_t ws_size,
                              hipStream_t stream) {
    const float* x    = (const float*)d_in[0];
    const int*   esrc = (const int*)d_in[1];
    const int*   edst = (const int*)d_in[2];
    const float* ew   = (const float*)d_in[3];
    const float* w_in = (const float*)d_in[4];
    const float* b_in = (const float*)d_in[5];
    const float* gcnw = (const float*)d_in[6];   // [4,128,128]
    const float* wout = (const float*)d_in[7];
    const float* bout = (const float*)d_in[8];
    float* out = (float*)d_out;

    // workspace layout
    unsigned short* h0 = (unsigned short*)d_ws;        // NF ushorts each
    unsigned short* hA = h0 + NF;
    unsigned short* hB = hA + NF;
    unsigned short* hi = hB + NF;
    unsigned short* wp = hi + NF;                      // 90112 ushorts packed W
    int2* colw = (int2*)(wp + 90112);                  // E int2
    int2* ebuf = colw + N_EDGES;                       // E int2 (bucket-grouped)
    int*  row_ptr       = (int*)(ebuf + N_EDGES);      // N+1
    int*  deg           = row_ptr + (N_NODES + 1);     // N
    int*  blocksum      = deg + N_NODES;               // SCAN_B
    int*  bucket_cnt    = blocksum + SCAN_B;           // NB
    int*  bucket_base   = bucket_cnt + NB;             // NB+1
    int*  bucket_cursor = bucket_base + (NB + 1);      // NB

    const int PART_B = (N_EDGES + CHUNK - 1) / CHUNK;  // 782
    const int MFMA_BLOCKS = (STRIPES + 3) / 4;

    // ---- weight pack ----
    k_prepw<<<(90112 + 255) / 256, 256, 0, stream>>>(gcnw, wout, w_in, wp);

    // ---- bucketed CSR build ----
    hipMemsetAsync(bucket_cnt, 0, NB * sizeof(int), stream);
    k_hist<<<PART_B, 256, 0, stream>>>(edst, bucket_cnt);
    k_scanb<<<1, 512, 0, stream>>>(bucket_cnt, bucket_base, bucket_cursor);
    k_part<<<PART_B, 256, 0, stream>>>(esrc, edst, ew, bucket_cursor, ebuf);
    k_deg<<<NB, 256, 0, stream>>>(ebuf, bucket_base, deg);
    k_scan1<<<SCAN_B, 1024, 0, stream>>>(deg, row_ptr, blocksum);
    k_scan2<<<1, 128, 0, stream>>>(blocksum);
    k_scan3<<<SCAN_B, 1024, 0, stream>>>(row_ptr, blocksum);
    k_scatter2<<<NB, 256, 0, stream>>>(ebuf, bucket_base, row_ptr, colw);

    // h0 = relu(x @ w_in + b_in)
    k_in_mfma<<<MFMA_BLOCKS, 256, 0, stream>>>(x, wp + 73728, b_in, h0);

    const unsigned short* hprev = h0;
    unsigned short* bufs[2] = {hA, hB};
    for (int l = 0; l < 4; l++) {
        float theta = logf(0.5f / (float)(l + 2) + 1.0f);
        k_spmm_csr<<<(N_NODES + 3) / 4, 256, 0, stream>>>(row_ptr, colw, hprev, h0, hi);
        unsigned short* hnew = bufs[l & 1];
        k_layer_mfma<<<MFMA_BLOCKS, 256, 0, stream>>>(hi, hprev, wp + (size_t)l * 16384,
                                                      hnew, theta);
        hprev = hnew;
    }

    // out = log_softmax(h @ w_out + b_out)
    k_out_mfma<<<MFMA_BLOCKS, 256, 0, stream>>>(hprev, wp + 65536, bout, out);
}

// Round 6
// 592.581 us; speedup vs baseline: 1.4537x; 1.0152x over previous
//
#include <hip/hip_runtime.h>
#include <math.h>

#define N_NODES 100000
#define N_EDGES 1600000
#define DIM     128
#define NCLS    64
#define ALPHA   0.1f

#define SCAN_B  98                 // ceil(100000/1024)
#define NB      391                // ceil(100000/256) dst-buckets of 256 nodes
#define NF      ((size_t)N_NODES * DIM)
#define STRIPES (N_NODES / 16)     // 6250 exact
#define CHUNK   2048               // edges per partition block

typedef __attribute__((ext_vector_type(8))) short  bf16x8;
typedef __attribute__((ext_vector_type(4))) float  f32x4;

// ---- bf16 helpers (storage only; accumulation fp32) ----
__device__ __forceinline__ float bf2f(unsigned short u) {
    return __uint_as_float((unsigned int)u << 16);
}
__device__ __forceinline__ float2 bf2f2(ushort2 u) {
    return make_float2(bf2f(u.x), bf2f(u.y));
}
__device__ __forceinline__ unsigned short f2bf(float x) {
    unsigned int u = __float_as_uint(x);
    u += 0x7FFFu + ((u >> 16) & 1u);          // round-to-nearest-even
    return (unsigned short)(u >> 16);
}
__device__ __forceinline__ ushort2 f2bf2(float2 v) {
    return make_ushort2(f2bf(v.x), f2bf(v.y));
}

// unpack packed bf16 pair from a u32 without shifts on the high half
#define BFLO(u) __uint_as_float((u) << 16)
#define BFHI(u) __uint_as_float((u) & 0xFFFF0000u)

// ================= bucketed CSR build =================
// bucket = dst >> 8 (256 nodes/bucket). ebuf entry: x = src | dst_local<<17, y = 0.9*w.

__global__ __launch_bounds__(256) void k_hist(const int* __restrict__ dst,
                                              int* __restrict__ bucket_cnt) {
    __shared__ int hist[NB];
    int t = threadIdx.x;
    for (int b = t; b < NB; b += 256) hist[b] = 0;
    __syncthreads();
    int base = blockIdx.x * CHUNK;
    int end = min(base + CHUNK, N_EDGES);
    for (int i = base + t; i < end; i += 256)
        atomicAdd(&hist[dst[i] >> 8], 1);
    __syncthreads();
    for (int b = t; b < NB; b += 256)
        if (hist[b]) atomicAdd(&bucket_cnt[b], hist[b]);
}

__global__ __launch_bounds__(512) void k_scanb(const int* __restrict__ bucket_cnt,
                                               int* __restrict__ bucket_base,
                                               int* __restrict__ bucket_cursor) {
    __shared__ int s[512];
    int t = threadIdx.x;
    int v = (t < NB) ? bucket_cnt[t] : 0;
    s[t] = v;
    __syncthreads();
    for (int off = 1; off < 512; off <<= 1) {
        int u = (t >= off) ? s[t - off] : 0;
        __syncthreads();
        s[t] += u;
        __syncthreads();
    }
    if (t < NB) {
        int base = s[t] - v;
        bucket_base[t] = base;
        bucket_cursor[t] = base;
    }
    if (t == 0) bucket_base[NB] = N_EDGES;
}

__global__ __launch_bounds__(256) void k_part(const int* __restrict__ src,
                                              const int* __restrict__ dst,
                                              const float* __restrict__ ew,
                                              int* __restrict__ bucket_cursor,
                                              int2* __restrict__ ebuf) {
    __shared__ int lhist[NB], gbase[NB];
    int t = threadIdx.x;
    for (int b = t; b < NB; b += 256) lhist[b] = 0;
    __syncthreads();
    int base = blockIdx.x * CHUNK;
    int end = min(base + CHUNK, N_EDGES);
    for (int i = base + t; i < end; i += 256)
        atomicAdd(&lhist[dst[i] >> 8], 1);
    __syncthreads();
    for (int b = t; b < NB; b += 256) {
        int c = lhist[b];
        gbase[b] = c ? atomicAdd(&bucket_cursor[b], c) : 0;
        lhist[b] = 0;
    }
    __syncthreads();
    for (int i = base + t; i < end; i += 256) {
        int d = dst[i];
        int b = d >> 8;
        int r = atomicAdd(&lhist[b], 1);
        ebuf[gbase[b] + r] = make_int2(src[i] | ((d & 255) << 17),
                                       __float_as_int((1.0f - ALPHA) * ew[i]));
    }
}

// per-bucket degree via LDS counters (no global atomics)
__global__ __launch_bounds__(256) void k_deg(const int2* __restrict__ ebuf,
                                             const int* __restrict__ bucket_base,
                                             int* __restrict__ deg) {
    __shared__ int cnt[256];
    int t = threadIdx.x, b = blockIdx.x;
    cnt[t] = 0;
    __syncthreads();
    int beg = bucket_base[b], end = bucket_base[b + 1];
    for (int i = beg + t; i < end; i += 256)
        atomicAdd(&cnt[ebuf[i].x >> 17], 1);
    __syncthreads();
    int node = b * 256 + t;
    if (node < N_NODES) deg[node] = cnt[t];
}

__global__ __launch_bounds__(1024) void k_scan1(const int* __restrict__ deg,
                                                int* __restrict__ row_ptr,
                                                int* __restrict__ blocksum) {
    __shared__ int s[1024];
    int t = threadIdx.x;
    int i = blockIdx.x * 1024 + t;
    int v = (i < N_NODES) ? deg[i] : 0;
    s[t] = v;
    __syncthreads();
    for (int off = 1; off < 1024; off <<= 1) {
        int u = (t >= off) ? s[t - off] : 0;
        __syncthreads();
        s[t] += u;
        __syncthreads();
    }
    if (i < N_NODES) row_ptr[i] = s[t] - v;
    if (t == 1023) blocksum[blockIdx.x] = s[1023];
}

__global__ __launch_bounds__(128) void k_scan2(int* __restrict__ blocksum) {
    __shared__ int s[128];
    int t = threadIdx.x;
    int v = (t < SCAN_B) ? blocksum[t] : 0;
    s[t] = v;
    __syncthreads();
    for (int off = 1; off < 128; off <<= 1) {
        int u = (t >= off) ? s[t - off] : 0;
        __syncthreads();
        s[t] += u;
        __syncthreads();
    }
    if (t < SCAN_B) blocksum[t] = s[t] - v;
}

__global__ __launch_bounds__(1024) void k_scan3(int* __restrict__ row_ptr,
                                                const int* __restrict__ blocksum) {
    int t = threadIdx.x;
    int i = blockIdx.x * 1024 + t;
    if (i < N_NODES) row_ptr[i] += blocksum[blockIdx.x];
    if (i == 0) row_ptr[N_NODES] = N_EDGES;
}

// per-bucket counting-sort scatter; LDS cursors, colw writes confined to ~32KB
__global__ __launch_bounds__(256) void k_scatter2(const int2* __restrict__ ebuf,
                                                  const int* __restrict__ bucket_base,
                                                  const int* __restrict__ row_ptr,
                                                  int2* __restrict__ colw) {
    __shared__ int lcur[256];
    int t = threadIdx.x, b = blockIdx.x;
    int node = b * 256 + t;
    lcur[t] = (node < N_NODES) ? row_ptr[node] : 0;
    __syncthreads();
    int beg = bucket_base[b], end = bucket_base[b + 1];
    for (int i = beg + t; i < end; i += 256) {
        int2 e = ebuf[i];
        int pos = atomicAdd(&lcur[e.x >> 17], 1);
        colw[pos] = make_int2(e.x & 0x1FFFF, e.y);
    }
}

// ===== weight pack: fp32 -> bf16 B-fragment order =====
// frag idx = ((nt*4 + ch)*64 + lane)*8 + j ;
// value = W[ch*32 + (lane>>4)*8 + j][nt*16 + (lane&15)]
// layers at wp[l*16384] (l=0..3), w_out at wp[65536] (nt 0..3), w_in at wp[73728].
__global__ void k_prepw(const float* __restrict__ gcnw, const float* __restrict__ wout,
                        const float* __restrict__ win, unsigned short* __restrict__ wp) {
    int tid = blockIdx.x * 256 + threadIdx.x;
    if (tid < 65536) {
        int l = tid >> 14;
        int r = tid & 16383;
        int j = r & 7, lane = (r >> 3) & 63, ch = (r >> 9) & 3, nt = r >> 11;
        int n = nt * 16 + (lane & 15);
        int k = ch * 32 + (lane >> 4) * 8 + j;
        wp[tid] = f2bf(gcnw[l * 16384 + k * 128 + n]);
    } else if (tid < 73728) {
        int r = tid - 65536;
        int j = r & 7, lane = (r >> 3) & 63, ch = (r >> 9) & 3, nt = r >> 11; // nt 0..3
        int n = nt * 16 + (lane & 15);
        int k = ch * 32 + (lane >> 4) * 8 + j;
        wp[tid] = f2bf(wout[k * 64 + n]);
    } else if (tid < 90112) {
        int r = tid - 73728;
        int j = r & 7, lane = (r >> 3) & 63, ch = (r >> 9) & 3, nt = r >> 11; // nt 0..7
        int n = nt * 16 + (lane & 15);
        int k = ch * 32 + (lane >> 4) * 8 + j;
        wp[tid] = f2bf(win[k * 128 + n]);
    }
}

// ===== SpMM gather (bf16 rows): hi[i] = ALPHA*h0[i] + sum_e w*h[src] =====
// R4: 16 lanes/row x 4 edge-slots, uint4 (16B) lane-loads -> 4x fewer VMEM
// instructions + address VALU per edge. Slot partials tree-reduced via shfl_xor.
__global__ __launch_bounds__(256, 8) void k_spmm_csr(
    const int* __restrict__ row_ptr, const int2* __restrict__ colw,
    const unsigned short* __restrict__ h, const unsigned short* __restrict__ h0,
    unsigned short* __restrict__ out) {
    int node = blockIdx.x * 4 + (threadIdx.x >> 6);
    if (node >= N_NODES) return;
    int lane = threadIdx.x & 63;
    int slot = lane >> 4;           // edge slot 0..3
    int seg  = lane & 15;           // 16B segment of the row (8 bf16)
    int beg = row_ptr[node], end = row_ptr[node + 1];

    float acc[8] = {0.f, 0.f, 0.f, 0.f, 0.f, 0.f, 0.f, 0.f};
    if (slot == 0) {                // initial residual added once
        uint4 z = *(const uint4*)(h0 + (size_t)node * DIM + seg * 8);
        acc[0] = ALPHA * BFLO(z.x); acc[1] = ALPHA * BFHI(z.x);
        acc[2] = ALPHA * BFLO(z.y); acc[3] = ALPHA * BFHI(z.y);
        acc[4] = ALPHA * BFLO(z.z); acc[5] = ALPHA * BFHI(z.z);
        acc[6] = ALPHA * BFLO(z.w); acc[7] = ALPHA * BFHI(z.w);
    }

    int e = beg;
    for (; e + 8 <= end; e += 8) {             // 8 edges in flight (2 quads)
        int2 ca = colw[e + slot];
        int2 cb = colw[e + 4 + slot];
        uint4 ra = *(const uint4*)(h + (size_t)ca.x * DIM + seg * 8);
        uint4 rb = *(const uint4*)(h + (size_t)cb.x * DIM + seg * 8);
        float wa = __int_as_float(ca.y), wb = __int_as_float(cb.y);
        acc[0] += wa * BFLO(ra.x); acc[1] += wa * BFHI(ra.x);
        acc[2] += wa * BFLO(ra.y); acc[3] += wa * BFHI(ra.y);
        acc[4] += wa * BFLO(ra.z); acc[5] += wa * BFHI(ra.z);
        acc[6] += wa * BFLO(ra.w); acc[7] += wa * BFHI(ra.w);
        acc[0] += wb * BFLO(rb.x); acc[1] += wb * BFHI(rb.x);
        acc[2] += wb * BFLO(rb.y); acc[3] += wb * BFHI(rb.y);
        acc[4] += wb * BFLO(rb.z); acc[5] += wb * BFHI(rb.z);
        acc[6] += wb * BFLO(rb.w); acc[7] += wb * BFHI(rb.w);
    }
    for (; e < end; e += 4) {                  // predicated tail quads
        int eh = e + slot;
        float w = 0.f;
        const unsigned short* rp = h;          // dummy row 0, w=0
        if (eh < end) {
            int2 c = colw[eh];
            w = __int_as_float(c.y);
            rp = h + (size_t)c.x * DIM;
        }
        uint4 r = *(const uint4*)(rp + seg * 8);
        acc[0] += w * BFLO(r.x); acc[1] += w * BFHI(r.x);
        acc[2] += w * BFLO(r.y); acc[3] += w * BFHI(r.y);
        acc[4] += w * BFLO(r.z); acc[5] += w * BFHI(r.z);
        acc[6] += w * BFLO(r.w); acc[7] += w * BFHI(r.w);
    }

    // combine the 4 edge-slots (lanes l, l+16, l+32, l+48 hold same dims)
    #pragma unroll
    for (int j = 0; j < 8; j++) {
        acc[j] += __shfl_xor(acc[j], 16);
        acc[j] += __shfl_xor(acc[j], 32);
    }

    if (slot == 0) {                           // 16 lanes write 16B each
        unsigned int p0 = (unsigned int)f2bf(acc[0]) | ((unsigned int)f2bf(acc[1]) << 16);
        unsigned int p1 = (unsigned int)f2bf(acc[2]) | ((unsigned int)f2bf(acc[3]) << 16);
        unsigned int p2 = (unsigned int)f2bf(acc[4]) | ((unsigned int)f2bf(acc[5]) << 16);
        unsigned int p3 = (unsigned int)f2bf(acc[6]) | ((unsigned int)f2bf(acc[7]) << 16);
        *(uint4*)(out + (size_t)node * DIM + seg * 8) = make_uint4(p0, p1, p2, p3);
    }
}

// ===== MFMA input GEMM: h0 = relu(x @ W_in + b)  (x fp32 -> bf16 in-reg) =====
__global__ __launch_bounds__(256) void k_in_mfma(
    const float* __restrict__ x, const unsigned short* __restrict__ wp,
    const float* __restrict__ b_in, unsigned short* __restrict__ h0) {
    int wave = threadIdx.x >> 6, lane = threadIdx.x & 63;
    int stripe = blockIdx.x * 4 + wave;
    if (stripe >= STRIPES) return;
    int r0 = stripe * 16;
    int m = lane & 15, q = lane >> 4;

    f32x4 acc[8];
    #pragma unroll
    for (int nt = 0; nt < 8; nt++) acc[nt] = (f32x4){0.f, 0.f, 0.f, 0.f};

    const float* xr = x + (size_t)(r0 + m) * DIM + q * 8;
    #pragma unroll
    for (int ch = 0; ch < 4; ch++) {
        float4 a0 = *(const float4*)(xr + ch * 32);
        float4 a1 = *(const float4*)(xr + ch * 32 + 4);
        bf16x8 a;
        a[0] = (short)f2bf(a0.x); a[1] = (short)f2bf(a0.y);
        a[2] = (short)f2bf(a0.z); a[3] = (short)f2bf(a0.w);
        a[4] = (short)f2bf(a1.x); a[5] = (short)f2bf(a1.y);
        a[6] = (short)f2bf(a1.z); a[7] = (short)f2bf(a1.w);
        #pragma unroll
        for (int nt = 0; nt < 8; nt++) {
            bf16x8 b = *(const bf16x8*)(wp + (((nt * 4 + ch) * 64 + lane) << 3));
            acc[nt] = __builtin_amdgcn_mfma_f32_16x16x32_bf16(a, b, acc[nt], 0, 0, 0);
        }
    }

    #pragma unroll
    for (int nt = 0; nt < 8; nt++) {
        int col = nt * 16 + m;
        float bias = b_in[col];
        #pragma unroll
        for (int r = 0; r < 4; r++) {
            int row = r0 + q * 4 + r;
            h0[(size_t)row * DIM + col] = f2bf(fmaxf(acc[nt][r] + bias, 0.f));
        }
    }
}

// ===== MFMA layer GEMM: h = relu(theta*(s@W) + (1-theta)*s + hprev) =====
__global__ __launch_bounds__(256) void k_layer_mfma(
    const unsigned short* __restrict__ s_in, const unsigned short* __restrict__ hprev,
    const unsigned short* __restrict__ wp, unsigned short* __restrict__ hout,
    float theta) {
    int wave = threadIdx.x >> 6, lane = threadIdx.x & 63;
    int stripe = blockIdx.x * 4 + wave;
    if (stripe >= STRIPES) return;
    int r0 = stripe * 16;
    int m = lane & 15, q = lane >> 4;
    float omt = 1.f - theta;

    f32x4 acc[8];
    #pragma unroll
    for (int nt = 0; nt < 8; nt++) acc[nt] = (f32x4){0.f, 0.f, 0.f, 0.f};

    const unsigned short* arow = s_in + (size_t)(r0 + m) * DIM + q * 8;
    #pragma unroll
    for (int ch = 0; ch < 4; ch++) {
        bf16x8 a = *(const bf16x8*)(arow + ch * 32);
        #pragma unroll
        for (int nt = 0; nt < 8; nt++) {
            bf16x8 b = *(const bf16x8*)(wp + (((nt * 4 + ch) * 64 + lane) << 3));
            acc[nt] = __builtin_amdgcn_mfma_f32_16x16x32_bf16(a, b, acc[nt], 0, 0, 0);
        }
    }

    #pragma unroll
    for (int nt = 0; nt < 8; nt++) {
        int col = nt * 16 + m;
        #pragma unroll
        for (int r = 0; r < 4; r++) {
            int row = r0 + q * 4 + r;
            size_t idx = (size_t)row * DIM + col;
            float sup = bf2f(s_in[idx]);
            float hp  = bf2f(hprev[idx]);
            float o = theta * acc[nt][r] + omt * sup + hp;
            hout[idx] = f2bf(fmaxf(o, 0.f));
        }
    }
}

// ===== MFMA output GEMM + log_softmax =====
__global__ __launch_bounds__(256) void k_out_mfma(
    const unsigned short* __restrict__ h, const unsigned short* __restrict__ wp,
    const float* __restrict__ bo, float* __restrict__ out) {
    int wave = threadIdx.x >> 6, lane = threadIdx.x & 63;
    int stripe = blockIdx.x * 4 + wave;
    if (stripe >= STRIPES) return;
    int r0 = stripe * 16;
    int m = lane & 15, q = lane >> 4;

    f32x4 acc[4];
    #pragma unroll
    for (int nt = 0; nt < 4; nt++) acc[nt] = (f32x4){0.f, 0.f, 0.f, 0.f};

    const unsigned short* arow = h + (size_t)(r0 + m) * DIM + q * 8;
    #pragma unroll
    for (int ch = 0; ch < 4; ch++) {
        bf16x8 a = *(const bf16x8*)(arow + ch * 32);
        #pragma unroll
        for (int nt = 0; nt < 4; nt++) {
            bf16x8 b = *(const bf16x8*)(wp + (((nt * 4 + ch) * 64 + lane) << 3));
            acc[nt] = __builtin_amdgcn_mfma_f32_16x16x32_bf16(a, b, acc[nt], 0, 0, 0);
        }
    }

    float v[4][4];
    #pragma unroll
    for (int nt = 0; nt < 4; nt++) {
        float bias = bo[nt * 16 + m];
        #pragma unroll
        for (int r = 0; r < 4; r++) v[nt][r] = acc[nt][r] + bias;
    }
    #pragma unroll
    for (int r = 0; r < 4; r++) {
        float mx = fmaxf(fmaxf(v[0][r], v[1][r]), fmaxf(v[2][r], v[3][r]));
        #pragma unroll
        for (int off = 1; off < 16; off <<= 1) mx = fmaxf(mx, __shfl_xor(mx, off));
        float s = 0.f;
        #pragma unroll
        for (int nt = 0; nt < 4; nt++) s += __expf(v[nt][r] - mx);
        #pragma unroll
        for (int off = 1; off < 16; off <<= 1) s += __shfl_xor(s, off);
        float lse = mx + logf(s);
        int row = r0 + q * 4 + r;
        #pragma unroll
        for (int nt = 0; nt < 4; nt++)
            out[(size_t)row * NCLS + nt * 16 + m] = v[nt][r] - lse;
    }
}

extern "C" void kernel_launch(void* const* d_in, const int* in_sizes, int n_in,
                              void* d_out, int out_size, void* d_ws, size_t ws_size,
                              hipStream_t stream) {
    const float* x    = (const float*)d_in[0];
    const int*   esrc = (const int*)d_in[1];
    const int*   edst = (const int*)d_in[2];
    const float* ew   = (const float*)d_in[3];
    const float* w_in = (const float*)d_in[4];
    const float* b_in = (const float*)d_in[5];
    const float* gcnw = (const float*)d_in[6];   // [4,128,128]
    const float* wout = (const float*)d_in[7];
    const float* bout = (const float*)d_in[8];
    float* out = (float*)d_out;

    // workspace layout
    unsigned short* h0 = (unsigned short*)d_ws;        // NF ushorts each
    unsigned short* hA = h0 + NF;
    unsigned short* hB = hA + NF;
    unsigned short* hi = hB + NF;
    unsigned short* wp = hi + NF;                      // 90112 ushorts packed W
    int2* colw = (int2*)(wp + 90112);                  // E int2
    int2* ebuf = colw + N_EDGES;                       // E int2 (bucket-grouped)
    int*  row_ptr       = (int*)(ebuf + N_EDGES);      // N+1
    int*  deg           = row_ptr + (N_NODES + 1);     // N
    int*  blocksum      = deg + N_NODES;               // SCAN_B
    int*  bucket_cnt    = blocksum + SCAN_B;           // NB
    int*  bucket_base   = bucket_cnt + NB;             // NB+1
    int*  bucket_cursor = bucket_base + (NB + 1);      // NB

    const int PART_B = (N_EDGES + CHUNK - 1) / CHUNK;  // 782
    const int MFMA_BLOCKS = (STRIPES + 3) / 4;

    // ---- weight pack ----
    k_prepw<<<(90112 + 255) / 256, 256, 0, stream>>>(gcnw, wout, w_in, wp);

    // ---- bucketed CSR build ----
    hipMemsetAsync(bucket_cnt, 0, NB * sizeof(int), stream);
    k_hist<<<PART_B, 256, 0, stream>>>(edst, bucket_cnt);
    k_scanb<<<1, 512, 0, stream>>>(bucket_cnt, bucket_base, bucket_cursor);
    k_part<<<PART_B, 256, 0, stream>>>(esrc, edst, ew, bucket_cursor, ebuf);
    k_deg<<<NB, 256, 0, stream>>>(ebuf, bucket_base, deg);
    k_scan1<<<SCAN_B, 1024, 0, stream>>>(deg, row_ptr, blocksum);
    k_scan2<<<1, 128, 0, stream>>>(blocksum);
    k_scan3<<<SCAN_B, 1024, 0, stream>>>(row_ptr, blocksum);
    k_scatter2<<<NB, 256, 0, stream>>>(ebuf, bucket_base, row_ptr, colw);

    // h0 = relu(x @ w_in + b_in)
    k_in_mfma<<<MFMA_BLOCKS, 256, 0, stream>>>(x, wp + 73728, b_in, h0);

    const unsigned short* hprev = h0;
    unsigned short* bufs[2] = {hA, hB};
    for (int l = 0; l < 4; l++) {
        float theta = logf(0.5f / (float)(l + 2) + 1.0f);
        k_spmm_csr<<<(N_NODES + 3) / 4, 256, 0, stream>>>(row_ptr, colw, hprev, h0, hi);
        unsigned short* hnew = bufs[l & 1];
        k_layer_mfma<<<MFMA_BLOCKS, 256, 0, stream>>>(hi, hprev, wp + (size_t)l * 16384,
                                                      hnew, theta);
        hprev = hnew;
    }

    // out = log_softmax(h @ w_out + b_out)
    k_out_mfma<<<MFMA_BLOCKS, 256, 0, stream>>>(hprev, wp + 65536, bout, out);
}

// Round 7
// 577.842 us; speedup vs baseline: 1.4908x; 1.0255x over previous
//
#include <hip/hip_runtime.h>
#include <math.h>

#define N_NODES 100000
#define N_EDGES 1600000
#define DIM     128
#define NCLS    64
#define ALPHA   0.1f

#define SCAN_B  98                 // ceil(100000/1024)
#define NB      391                // ceil(100000/256) dst-buckets of 256 nodes
#define NF      ((size_t)N_NODES * DIM)
#define STRIPES (N_NODES / 16)     // 6250 exact
#define CHUNK   2048               // edges per partition block

typedef __attribute__((ext_vector_type(8))) short  bf16x8;
typedef __attribute__((ext_vector_type(4))) float  f32x4;

// ---- bf16 helpers (storage only; accumulation fp32) ----
__device__ __forceinline__ float bf2f(unsigned short u) {
    return __uint_as_float((unsigned int)u << 16);
}
__device__ __forceinline__ float2 bf2f2(ushort2 u) {
    return make_float2(bf2f(u.x), bf2f(u.y));
}
__device__ __forceinline__ unsigned short f2bf(float x) {
    unsigned int u = __float_as_uint(x);
    u += 0x7FFFu + ((u >> 16) & 1u);          // round-to-nearest-even
    return (unsigned short)(u >> 16);
}
__device__ __forceinline__ ushort2 f2bf2(float2 v) {
    return make_ushort2(f2bf(v.x), f2bf(v.y));
}

// unpack packed bf16 pair from a u32 without shifts on the high half
#define BFLO(u) __uint_as_float((u) << 16)
#define BFHI(u) __uint_as_float((u) & 0xFFFF0000u)

// ================= bucketed CSR build =================
// bucket = dst >> 8 (256 nodes/bucket). ebuf entry: x = src | dst_local<<17, y = 0.9*w.

__global__ __launch_bounds__(256) void k_hist(const int* __restrict__ dst,
                                              int* __restrict__ bucket_cnt) {
    __shared__ int hist[NB];
    int t = threadIdx.x;
    for (int b = t; b < NB; b += 256) hist[b] = 0;
    __syncthreads();
    int base = blockIdx.x * CHUNK;
    int end = min(base + CHUNK, N_EDGES);
    for (int i = base + t; i < end; i += 256)
        atomicAdd(&hist[dst[i] >> 8], 1);
    __syncthreads();
    for (int b = t; b < NB; b += 256)
        if (hist[b]) atomicAdd(&bucket_cnt[b], hist[b]);
}

__global__ __launch_bounds__(512) void k_scanb(const int* __restrict__ bucket_cnt,
                                               int* __restrict__ bucket_base,
                                               int* __restrict__ bucket_cursor) {
    __shared__ int s[512];
    int t = threadIdx.x;
    int v = (t < NB) ? bucket_cnt[t] : 0;
    s[t] = v;
    __syncthreads();
    for (int off = 1; off < 512; off <<= 1) {
        int u = (t >= off) ? s[t - off] : 0;
        __syncthreads();
        s[t] += u;
        __syncthreads();
    }
    if (t < NB) {
        int base = s[t] - v;
        bucket_base[t] = base;
        bucket_cursor[t] = base;
    }
    if (t == 0) bucket_base[NB] = N_EDGES;
}

__global__ __launch_bounds__(256) void k_part(const int* __restrict__ src,
                                              const int* __restrict__ dst,
                                              const float* __restrict__ ew,
                                              int* __restrict__ bucket_cursor,
                                              int2* __restrict__ ebuf) {
    __shared__ int lhist[NB], gbase[NB];
    int t = threadIdx.x;
    for (int b = t; b < NB; b += 256) lhist[b] = 0;
    __syncthreads();
    int base = blockIdx.x * CHUNK;
    int end = min(base + CHUNK, N_EDGES);
    for (int i = base + t; i < end; i += 256)
        atomicAdd(&lhist[dst[i] >> 8], 1);
    __syncthreads();
    for (int b = t; b < NB; b += 256) {
        int c = lhist[b];
        gbase[b] = c ? atomicAdd(&bucket_cursor[b], c) : 0;
        lhist[b] = 0;
    }
    __syncthreads();
    for (int i = base + t; i < end; i += 256) {
        int d = dst[i];
        int b = d >> 8;
        int r = atomicAdd(&lhist[b], 1);
        ebuf[gbase[b] + r] = make_int2(src[i] | ((d & 255) << 17),
                                       __float_as_int((1.0f - ALPHA) * ew[i]));
    }
}

// per-bucket degree via LDS counters (no global atomics)
__global__ __launch_bounds__(256) void k_deg(const int2* __restrict__ ebuf,
                                             const int* __restrict__ bucket_base,
                                             int* __restrict__ deg) {
    __shared__ int cnt[256];
    int t = threadIdx.x, b = blockIdx.x;
    cnt[t] = 0;
    __syncthreads();
    int beg = bucket_base[b], end = bucket_base[b + 1];
    for (int i = beg + t; i < end; i += 256)
        atomicAdd(&cnt[ebuf[i].x >> 17], 1);
    __syncthreads();
    int node = b * 256 + t;
    if (node < N_NODES) deg[node] = cnt[t];
}

__global__ __launch_bounds__(1024) void k_scan1(const int* __restrict__ deg,
                                                int* __restrict__ row_ptr,
                                                int* __restrict__ blocksum) {
    __shared__ int s[1024];
    int t = threadIdx.x;
    int i = blockIdx.x * 1024 + t;
    int v = (i < N_NODES) ? deg[i] : 0;
    s[t] = v;
    __syncthreads();
    for (int off = 1; off < 1024; off <<= 1) {
        int u = (t >= off) ? s[t - off] : 0;
        __syncthreads();
        s[t] += u;
        __syncthreads();
    }
    if (i < N_NODES) row_ptr[i] = s[t] - v;
    if (t == 1023) blocksum[blockIdx.x] = s[1023];
}

__global__ __launch_bounds__(128) void k_scan2(int* __restrict__ blocksum) {
    __shared__ int s[128];
    int t = threadIdx.x;
    int v = (t < SCAN_B) ? blocksum[t] : 0;
    s[t] = v;
    __syncthreads();
    for (int off = 1; off < 128; off <<= 1) {
        int u = (t >= off) ? s[t - off] : 0;
        __syncthreads();
        s[t] += u;
        __syncthreads();
    }
    if (t < SCAN_B) blocksum[t] = s[t] - v;
}

__global__ __launch_bounds__(1024) void k_scan3(int* __restrict__ row_ptr,
                                                const int* __restrict__ blocksum) {
    int t = threadIdx.x;
    int i = blockIdx.x * 1024 + t;
    if (i < N_NODES) row_ptr[i] += blocksum[blockIdx.x];
    if (i == 0) row_ptr[N_NODES] = N_EDGES;
}

// per-bucket counting-sort scatter; LDS cursors, colw writes confined to ~32KB
__global__ __launch_bounds__(256) void k_scatter2(const int2* __restrict__ ebuf,
                                                  const int* __restrict__ bucket_base,
                                                  const int* __restrict__ row_ptr,
                                                  int2* __restrict__ colw) {
    __shared__ int lcur[256];
    int t = threadIdx.x, b = blockIdx.x;
    int node = b * 256 + t;
    lcur[t] = (node < N_NODES) ? row_ptr[node] : 0;
    __syncthreads();
    int beg = bucket_base[b], end = bucket_base[b + 1];
    for (int i = beg + t; i < end; i += 256) {
        int2 e = ebuf[i];
        int pos = atomicAdd(&lcur[e.x >> 17], 1);
        colw[pos] = make_int2(e.x & 0x1FFFF, e.y);
    }
}

// ===== weight pack: fp32 -> bf16 B-fragment order =====
// frag idx = ((nt*4 + ch)*64 + lane)*8 + j ;
// value = W[ch*32 + (lane>>4)*8 + j][nt*16 + (lane&15)]
// layers at wp[l*16384] (l=0..3), w_out at wp[65536] (nt 0..3), w_in at wp[73728].
__global__ void k_prepw(const float* __restrict__ gcnw, const float* __restrict__ wout,
                        const float* __restrict__ win, unsigned short* __restrict__ wp) {
    int tid = blockIdx.x * 256 + threadIdx.x;
    if (tid < 65536) {
        int l = tid >> 14;
        int r = tid & 16383;
        int j = r & 7, lane = (r >> 3) & 63, ch = (r >> 9) & 3, nt = r >> 11;
        int n = nt * 16 + (lane & 15);
        int k = ch * 32 + (lane >> 4) * 8 + j;
        wp[tid] = f2bf(gcnw[l * 16384 + k * 128 + n]);
    } else if (tid < 73728) {
        int r = tid - 65536;
        int j = r & 7, lane = (r >> 3) & 63, ch = (r >> 9) & 3, nt = r >> 11; // nt 0..3
        int n = nt * 16 + (lane & 15);
        int k = ch * 32 + (lane >> 4) * 8 + j;
        wp[tid] = f2bf(wout[k * 64 + n]);
    } else if (tid < 90112) {
        int r = tid - 73728;
        int j = r & 7, lane = (r >> 3) & 63, ch = (r >> 9) & 3, nt = r >> 11; // nt 0..7
        int n = nt * 16 + (lane & 15);
        int k = ch * 32 + (lane >> 4) * 8 + j;
        wp[tid] = f2bf(win[k * 128 + n]);
    }
}

// ===== SpMM gather (bf16 rows): hi[i] = ALPHA*h0[i] + sum_e w*h[src] =====
// R6: uniform 16-edge (4-quad) predicated pipeline. Clamped colw index +
// w=0 for tail lanes (branch-free); 4 colw + 4 row gathers in flight/wave.
__global__ __launch_bounds__(256, 8) void k_spmm_csr(
    const int* __restrict__ row_ptr, const int2* __restrict__ colw,
    const unsigned short* __restrict__ h, const unsigned short* __restrict__ h0,
    unsigned short* __restrict__ out) {
    int node = blockIdx.x * 4 + (threadIdx.x >> 6);
    if (node >= N_NODES) return;
    int lane = threadIdx.x & 63;
    int slot = lane >> 4;           // edge slot 0..3
    int seg  = lane & 15;           // 16B segment of the row (8 bf16)
    int beg = row_ptr[node], end = row_ptr[node + 1];

    float acc[8] = {0.f, 0.f, 0.f, 0.f, 0.f, 0.f, 0.f, 0.f};
    if (slot == 0) {                // initial residual added once
        uint4 z = *(const uint4*)(h0 + (size_t)node * DIM + seg * 8);
        acc[0] = ALPHA * BFLO(z.x); acc[1] = ALPHA * BFHI(z.x);
        acc[2] = ALPHA * BFLO(z.y); acc[3] = ALPHA * BFHI(z.y);
        acc[4] = ALPHA * BFLO(z.z); acc[5] = ALPHA * BFHI(z.z);
        acc[6] = ALPHA * BFLO(z.w); acc[7] = ALPHA * BFHI(z.w);
    }

    int last = end - 1;
    for (int e = beg; e < end; e += 16) {
        int e0 = e + slot, e1 = e0 + 4, e2 = e0 + 8, e3 = e0 + 12;
        int2 c0 = colw[min(e0, last)];
        int2 c1 = colw[min(e1, last)];
        int2 c2 = colw[min(e2, last)];
        int2 c3 = colw[min(e3, last)];
        uint4 r0 = *(const uint4*)(h + (size_t)c0.x * DIM + seg * 8);
        uint4 r1 = *(const uint4*)(h + (size_t)c1.x * DIM + seg * 8);
        uint4 r2 = *(const uint4*)(h + (size_t)c2.x * DIM + seg * 8);
        uint4 r3 = *(const uint4*)(h + (size_t)c3.x * DIM + seg * 8);
        float w0 = (e0 < end) ? __int_as_float(c0.y) : 0.f;
        float w1 = (e1 < end) ? __int_as_float(c1.y) : 0.f;
        float w2 = (e2 < end) ? __int_as_float(c2.y) : 0.f;
        float w3 = (e3 < end) ? __int_as_float(c3.y) : 0.f;
        acc[0] += w0 * BFLO(r0.x); acc[1] += w0 * BFHI(r0.x);
        acc[2] += w0 * BFLO(r0.y); acc[3] += w0 * BFHI(r0.y);
        acc[4] += w0 * BFLO(r0.z); acc[5] += w0 * BFHI(r0.z);
        acc[6] += w0 * BFLO(r0.w); acc[7] += w0 * BFHI(r0.w);
        acc[0] += w1 * BFLO(r1.x); acc[1] += w1 * BFHI(r1.x);
        acc[2] += w1 * BFLO(r1.y); acc[3] += w1 * BFHI(r1.y);
        acc[4] += w1 * BFLO(r1.z); acc[5] += w1 * BFHI(r1.z);
        acc[6] += w1 * BFLO(r1.w); acc[7] += w1 * BFHI(r1.w);
        acc[0] += w2 * BFLO(r2.x); acc[1] += w2 * BFHI(r2.x);
        acc[2] += w2 * BFLO(r2.y); acc[3] += w2 * BFHI(r2.y);
        acc[4] += w2 * BFLO(r2.z); acc[5] += w2 * BFHI(r2.z);
        acc[6] += w2 * BFLO(r2.w); acc[7] += w2 * BFHI(r2.w);
        acc[0] += w3 * BFLO(r3.x); acc[1] += w3 * BFHI(r3.x);
        acc[2] += w3 * BFLO(r3.y); acc[3] += w3 * BFHI(r3.y);
        acc[4] += w3 * BFLO(r3.z); acc[5] += w3 * BFHI(r3.z);
        acc[6] += w3 * BFLO(r3.w); acc[7] += w3 * BFHI(r3.w);
    }

    // combine the 4 edge-slots (lanes l, l+16, l+32, l+48 hold same dims)
    #pragma unroll
    for (int j = 0; j < 8; j++) {
        acc[j] += __shfl_xor(acc[j], 16);
        acc[j] += __shfl_xor(acc[j], 32);
    }

    if (slot == 0) {                           // 16 lanes write 16B each
        unsigned int p0 = (unsigned int)f2bf(acc[0]) | ((unsigned int)f2bf(acc[1]) << 16);
        unsigned int p1 = (unsigned int)f2bf(acc[2]) | ((unsigned int)f2bf(acc[3]) << 16);
        unsigned int p2 = (unsigned int)f2bf(acc[4]) | ((unsigned int)f2bf(acc[5]) << 16);
        unsigned int p3 = (unsigned int)f2bf(acc[6]) | ((unsigned int)f2bf(acc[7]) << 16);
        *(uint4*)(out + (size_t)node * DIM + seg * 8) = make_uint4(p0, p1, p2, p3);
    }
}

// ===== MFMA input GEMM: h0 = relu(x @ W_in + b)  (x fp32 -> bf16 in-reg) =====
__global__ __launch_bounds__(256) void k_in_mfma(
    const float* __restrict__ x, const unsigned short* __restrict__ wp,
    const float* __restrict__ b_in, unsigned short* __restrict__ h0) {
    int wave = threadIdx.x >> 6, lane = threadIdx.x & 63;
    int stripe = blockIdx.x * 4 + wave;
    if (stripe >= STRIPES) return;
    int r0 = stripe * 16;
    int m = lane & 15, q = lane >> 4;

    f32x4 acc[8];
    #pragma unroll
    for (int nt = 0; nt < 8; nt++) acc[nt] = (f32x4){0.f, 0.f, 0.f, 0.f};

    const float* xr = x + (size_t)(r0 + m) * DIM + q * 8;
    #pragma unroll
    for (int ch = 0; ch < 4; ch++) {
        float4 a0 = *(const float4*)(xr + ch * 32);
        float4 a1 = *(const float4*)(xr + ch * 32 + 4);
        bf16x8 a;
        a[0] = (short)f2bf(a0.x); a[1] = (short)f2bf(a0.y);
        a[2] = (short)f2bf(a0.z); a[3] = (short)f2bf(a0.w);
        a[4] = (short)f2bf(a1.x); a[5] = (short)f2bf(a1.y);
        a[6] = (short)f2bf(a1.z); a[7] = (short)f2bf(a1.w);
        #pragma unroll
        for (int nt = 0; nt < 8; nt++) {
            bf16x8 b = *(const bf16x8*)(wp + (((nt * 4 + ch) * 64 + lane) << 3));
            acc[nt] = __builtin_amdgcn_mfma_f32_16x16x32_bf16(a, b, acc[nt], 0, 0, 0);
        }
    }

    #pragma unroll
    for (int nt = 0; nt < 8; nt++) {
        int col = nt * 16 + m;
        float bias = b_in[col];
        #pragma unroll
        for (int r = 0; r < 4; r++) {
            int row = r0 + q * 4 + r;
            h0[(size_t)row * DIM + col] = f2bf(fmaxf(acc[nt][r] + bias, 0.f));
        }
    }
}

// ===== MFMA layer GEMM: h = relu(theta*(s@W) + (1-theta)*s + hprev) =====
__global__ __launch_bounds__(256) void k_layer_mfma(
    const unsigned short* __restrict__ s_in, const unsigned short* __restrict__ hprev,
    const unsigned short* __restrict__ wp, unsigned short* __restrict__ hout,
    float theta) {
    int wave = threadIdx.x >> 6, lane = threadIdx.x & 63;
    int stripe = blockIdx.x * 4 + wave;
    if (stripe >= STRIPES) return;
    int r0 = stripe * 16;
    int m = lane & 15, q = lane >> 4;
    float omt = 1.f - theta;

    f32x4 acc[8];
    #pragma unroll
    for (int nt = 0; nt < 8; nt++) acc[nt] = (f32x4){0.f, 0.f, 0.f, 0.f};

    const unsigned short* arow = s_in + (size_t)(r0 + m) * DIM + q * 8;
    #pragma unroll
    for (int ch = 0; ch < 4; ch++) {
        bf16x8 a = *(const bf16x8*)(arow + ch * 32);
        #pragma unroll
        for (int nt = 0; nt < 8; nt++) {
            bf16x8 b = *(const bf16x8*)(wp + (((nt * 4 + ch) * 64 + lane) << 3));
            acc[nt] = __builtin_amdgcn_mfma_f32_16x16x32_bf16(a, b, acc[nt], 0, 0, 0);
        }
    }

    #pragma unroll
    for (int nt = 0; nt < 8; nt++) {
        int col = nt * 16 + m;
        #pragma unroll
        for (int r = 0; r < 4; r++) {
            int row = r0 + q * 4 + r;
            size_t idx = (size_t)row * DIM + col;
            float sup = bf2f(s_in[idx]);
            float hp  = bf2f(hprev[idx]);
            float o = theta * acc[nt][r] + omt * sup + hp;
            hout[idx] = f2bf(fmaxf(o, 0.f));
        }
    }
}

// ===== MFMA output GEMM + log_softmax =====
__global__ __launch_bounds__(256) void k_out_mfma(
    const unsigned short* __restrict__ h, const unsigned short* __restrict__ wp,
    const float* __restrict__ bo, float* __restrict__ out) {
    int wave = threadIdx.x >> 6, lane = threadIdx.x & 63;
    int stripe = blockIdx.x * 4 + wave;
    if (stripe >= STRIPES) return;
    int r0 = stripe * 16;
    int m = lane & 15, q = lane >> 4;

    f32x4 acc[4];
    #pragma unroll
    for (int nt = 0; nt < 4; nt++) acc[nt] = (f32x4){0.f, 0.f, 0.f, 0.f};

    const unsigned short* arow = h + (size_t)(r0 + m) * DIM + q * 8;
    #pragma unroll
    for (int ch = 0; ch < 4; ch++) {
        bf16x8 a = *(const bf16x8*)(arow + ch * 32);
        #pragma unroll
        for (int nt = 0; nt < 4; nt++) {
            bf16x8 b = *(const bf16x8*)(wp + (((nt * 4 + ch) * 64 + lane) << 3));
            acc[nt] = __builtin_amdgcn_mfma_f32_16x16x32_bf16(a, b, acc[nt], 0, 0, 0);
        }
    }

    float v[4][4];
    #pragma unroll
    for (int nt = 0; nt < 4; nt++) {
        float bias = bo[nt * 16 + m];
        #pragma unroll
        for (int r = 0; r < 4; r++) v[nt][r] = acc[nt][r] + bias;
    }
    #pragma unroll
    for (int r = 0; r < 4; r++) {
        float mx = fmaxf(fmaxf(v[0][r], v[1][r]), fmaxf(v[2][r], v[3][r]));
        #pragma unroll
        for (int off = 1; off < 16; off <<= 1) mx = fmaxf(mx, __shfl_xor(mx, off));
        float s = 0.f;
        #pragma unroll
        for (int nt = 0; nt < 4; nt++) s += __expf(v[nt][r] - mx);
        #pragma unroll
        for (int off = 1; off < 16; off <<= 1) s += __shfl_xor(s, off);
        float lse = mx + logf(s);
        int row = r0 + q * 4 + r;
        #pragma unroll
        for (int nt = 0; nt < 4; nt++)
            out[(size_t)row * NCLS + nt * 16 + m] = v[nt][r] - lse;
    }
}

extern "C" void kernel_launch(void* const* d_in, const int* in_sizes, int n_in,
                              void* d_out, int out_size, void* d_ws, size_t ws_size,
                              hipStream_t stream) {
    const float* x    = (const float*)d_in[0];
    const int*   esrc = (const int*)d_in[1];
    const int*   edst = (const int*)d_in[2];
    const float* ew   = (const float*)d_in[3];
    const float* w_in = (const float*)d_in[4];
    const float* b_in = (const float*)d_in[5];
    const float* gcnw = (const float*)d_in[6];   // [4,128,128]
    const float* wout = (const float*)d_in[7];
    const float* bout = (const float*)d_in[8];
    float* out = (float*)d_out;

    // workspace layout
    unsigned short* h0 = (unsigned short*)d_ws;        // NF ushorts each
    unsigned short* hA = h0 + NF;
    unsigned short* hB = hA + NF;
    unsigned short* hi = hB + NF;
    unsigned short* wp = hi + NF;                      // 90112 ushorts packed W
    int2* colw = (int2*)(wp + 90112);                  // E int2
    int2* ebuf = colw + N_EDGES;                       // E int2 (bucket-grouped)
    int*  row_ptr       = (int*)(ebuf + N_EDGES);      // N+1
    int*  deg           = row_ptr + (N_NODES + 1);     // N
    int*  blocksum      = deg + N_NODES;               // SCAN_B
    int*  bucket_cnt    = blocksum + SCAN_B;           // NB
    int*  bucket_base   = bucket_cnt + NB;             // NB+1
    int*  bucket_cursor = bucket_base + (NB + 1);      // NB

    const int PART_B = (N_EDGES + CHUNK - 1) / CHUNK;  // 782
    const int MFMA_BLOCKS = (STRIPES + 3) / 4;

    // ---- weight pack ----
    k_prepw<<<(90112 + 255) / 256, 256, 0, stream>>>(gcnw, wout, w_in, wp);

    // ---- bucketed CSR build ----
    hipMemsetAsync(bucket_cnt, 0, NB * sizeof(int), stream);
    k_hist<<<PART_B, 256, 0, stream>>>(edst, bucket_cnt);
    k_scanb<<<1, 512, 0, stream>>>(bucket_cnt, bucket_base, bucket_cursor);
    k_part<<<PART_B, 256, 0, stream>>>(esrc, edst, ew, bucket_cursor, ebuf);
    k_deg<<<NB, 256, 0, stream>>>(ebuf, bucket_base, deg);
    k_scan1<<<SCAN_B, 1024, 0, stream>>>(deg, row_ptr, blocksum);
    k_scan2<<<1, 128, 0, stream>>>(blocksum);
    k_scan3<<<SCAN_B, 1024, 0, stream>>>(row_ptr, blocksum);
    k_scatter2<<<NB, 256, 0, stream>>>(ebuf, bucket_base, row_ptr, colw);

    // h0 = relu(x @ w_in + b_in)
    k_in_mfma<<<MFMA_BLOCKS, 256, 0, stream>>>(x, wp + 73728, b_in, h0);

    const unsigned short* hprev = h0;
    unsigned short* bufs[2] = {hA, hB};
    for (int l = 0; l < 4; l++) {
        float theta = logf(0.5f / (float)(l + 2) + 1.0f);
        k_spmm_csr<<<(N_NODES + 3) / 4, 256, 0, stream>>>(row_ptr, colw, hprev, h0, hi);
        unsigned short* hnew = bufs[l & 1];
        k_layer_mfma<<<MFMA_BLOCKS, 256, 0, stream>>>(hi, hprev, wp + (size_t)l * 16384,
                                                      hnew, theta);
        hprev = hnew;
    }

    // out = log_softmax(h @ w_out + b_out)
    k_out_mfma<<<MFMA_BLOCKS, 256, 0, stream>>>(hprev, wp + 65536, bout, out);
}